// Round 2
// baseline (542.869 us; speedup 1.0000x reference)
//
#include <hip/hip_runtime.h>

// Problem constants (match reference setup_inputs)
#define B_N 64
#define H_N 512
#define W_N 512
#define T_N 100
#define TB  101        // T+1 buckets (bucket in [0,100])
#define R_N 8
#define NLAB 9         // labels 0..8 (0 = background)
#define CHUNKS 32      // chunks per image -> grid 2048 = 8 blocks/CU
#define PIX_PER_IMG (H_N * W_N)
#define CPIX (PIX_PER_IMG / CHUNKS)    // 8192 pixels per block
#define NCELL 256      // LUT cells; 1/256 < min threshold spacing (1/99)

// LUT entry: for cell c (s in ~[c/256,(c+1)/256)):
//   klo  = #{thr <= c/256}; at most one threshold falls inside a cell, so
//   bucket(s) = klo + (s >= thrb), verified branchlessly against the stored
//   neighbor thresholds (exact for ANY sorted thresholds via rare fallback).
struct LutE { float tlo, thrb, thi; int klo; };

// All tail-phase state overlays the per-wave histograms (used earlier).
union TailU {
    int whist[4][NLAB * TB];          // 14544 B, pixel phase
    struct {                           // 8.9 KB, tail phases (disjoint fields)
        double contrib[T_N];
        int    rh[R_N * TB];
        float  spro[R_N][T_N];
        int    validc[R_N];
        int    bgh[TB];
        float  fpr[T_N];
        float  ms[T_N];
        int    order[T_N];
        int    nd;
    } t;
};

__global__ __launch_bounds__(256, 8) void fused_kernel(
    const float* __restrict__ preds, const int* __restrict__ labels,
    const float* __restrict__ thr,
    int* __restrict__ region_hist,   // (B, R, TB)
    int* __restrict__ bg_hist,       // (B, TB)
    float* __restrict__ spro_sum,    // (T)
    int* __restrict__ n_def,         // (1)
    int* __restrict__ img_ctr,       // (B)
    int* __restrict__ done_ctr,      // (1)
    float* __restrict__ out)
{
    __shared__ float s_thr[T_N];
    __shared__ __align__(16) LutE lut[NCELL];
    __shared__ TailU u;
    __shared__ int s_tick;

    const int tid  = threadIdx.x;
    const int wave = tid >> 6;

    if (tid < T_N) s_thr[tid] = thr[tid];
    for (int i = tid; i < 4 * NLAB * TB; i += 256) ((int*)u.whist)[i] = 0;
    __syncthreads();

    // Build the 256-cell LUT (one entry per thread, binary search over s_thr).
    if (tid < NCELL) {
        float lo = (float)tid * (1.0f / (float)NCELL);
        int a = 0, b = T_N;
        while (a < b) { int m = (a + b) >> 1; if (s_thr[m] <= lo) a = m + 1; else b = m; }
        LutE e;
        e.tlo  = (a > 0)        ? s_thr[a - 1] : -2.0f;   // sentinel: always <= s
        e.thrb = (a < T_N)      ? s_thr[a]     :  2.0f;   // sentinel: always  > s
        e.thi  = (a + 1 < T_N)  ? s_thr[a + 1] :  2.0f;
        e.klo  = a;
        lut[tid] = e;
    }
    __syncthreads();

    // ---------------- pixel phase ----------------
    const int img   = blockIdx.x >> 5;          // / CHUNKS
    const int chunk = blockIdx.x & (CHUNKS - 1);
    const long base = (long)img * PIX_PER_IMG + (long)chunk * CPIX;
    const float4* p4 = (const float4*)(preds + base);
    const int4*   l4 = (const int4*)(labels + base);
    int* __restrict__ myh = u.whist[wave];

#pragma unroll
    for (int g = 0; g < 2; ++g) {
        float4 pv[4];
        int4   lv[4];
#pragma unroll
        for (int q = 0; q < 4; ++q) {
            pv[q] = p4[(g * 4 + q) * 256 + tid];
            lv[q] = l4[(g * 4 + q) * 256 + tid];
        }
#pragma unroll
        for (int q = 0; q < 4; ++q) {
            float ps[4] = {pv[q].x, pv[q].y, pv[q].z, pv[q].w};
            int   ls[4] = {lv[q].x, lv[q].y, lv[q].z, lv[q].w};
#pragma unroll
            for (int j = 0; j < 4; ++j) {
                float s = ps[j];
                int c = (int)(s * (float)NCELL);
                c = max(0, min(NCELL - 1, c));
                LutE e = lut[c];                 // one ds_read_b128
                int ge = (s >= e.thrb) ? 1 : 0;
                int k = e.klo + ge;
                float lowv  = ge ? e.thrb : e.tlo;   // = thr[k-1] (or sentinel)
                float highv = ge ? e.thi  : e.thrb;  // = thr[k]   (or sentinel)
                if (__builtin_expect(!(lowv <= s && s < highv), 0)) {
                    // exact fixup — never taken for well-formed LUT cells
                    k = max(0, min(T_N, k));
                    while (k < T_N && s_thr[k] <= s) ++k;
                    while (k > 0 && s_thr[k - 1] > s) --k;
                }
                atomicAdd(&myh[ls[j] * TB + k], 1);
            }
        }
    }
    __syncthreads();

    // merge wave copies, flush to global
    for (int i = tid; i < NLAB * TB; i += 256) {
        int v = u.whist[0][i] + u.whist[1][i] + u.whist[2][i] + u.whist[3][i];
        if (v) {
            int lab = i / TB;
            int t   = i - lab * TB;
            if (lab == 0)
                atomicAdd(&bg_hist[img * TB + t], v);
            else
                atomicAdd(&region_hist[(img * R_N + (lab - 1)) * TB + t], v);
        }
    }

    // ---------------- per-image ticket ----------------
    __threadfence();        // every thread releases its flush atomics
    __syncthreads();
    if (tid == 0)
        s_tick = __hip_atomic_fetch_add(&img_ctr[img], 1, __ATOMIC_ACQ_REL,
                                        __HIP_MEMORY_SCOPE_AGENT);
    __syncthreads();
    if (s_tick != CHUNKS - 1) return;   // uniform per-block exit

    // ---- last chunk block of this image: region sPRO ----
    // (agent-scope atomic loads: other writers may be on other XCDs and no
    //  kernel boundary flushes caches for us anymore)
    for (int i = tid; i < R_N * TB; i += 256)
        u.t.rh[i] = __hip_atomic_load(&region_hist[img * R_N * TB + i],
                                      __ATOMIC_RELAXED, __HIP_MEMORY_SCOPE_AGENT);
    __syncthreads();

    if (tid < R_N) {
        const int* h = &u.t.rh[tid * TB];
        int area = 0;
        for (int t = 0; t < TB; ++t) area += h[t];
        float sat   = fmaxf((float)area, 1.0f);
        float valid = (area > 0) ? 1.0f : 0.0f;
        int csum = 0;
        for (int t = 0; t < T_N; ++t) {
            csum += h[t];
            u.t.spro[tid][t] = fminf((float)(area - csum) / sat, 1.0f) * valid;
        }
        u.t.validc[tid] = (area > 0) ? 1 : 0;
    }
    __syncthreads();

    if (tid < T_N) {
        float ssum = 0.0f;
        for (int r = 0; r < R_N; ++r) ssum += u.t.spro[r][tid];
        atomicAdd(&spro_sum[tid], ssum);   // dyadic terms -> exact, order-free
    }
    if (tid == 0) {
        int v = 0;
        for (int r = 0; r < R_N; ++r) v += u.t.validc[r];
        atomicAdd(n_def, v);
    }

    // ---------------- global ticket ----------------
    __threadfence();
    __syncthreads();
    if (tid == 0)
        s_tick = __hip_atomic_fetch_add(done_ctr, 1, __ATOMIC_ACQ_REL,
                                        __HIP_MEMORY_SCOPE_AGENT);
    __syncthreads();
    if (s_tick != B_N - 1) return;

    // ---- last block overall: fold bg hists + final AUC ----
    if (tid < TB) {
        int ssum = 0;
        for (int b = 0; b < B_N; ++b)
            ssum += __hip_atomic_load(&bg_hist[b * TB + tid],
                                      __ATOMIC_RELAXED, __HIP_MEMORY_SCOPE_AGENT);
        u.t.bgh[tid] = ssum;
    }
    if (tid < T_N)
        u.t.ms[tid] = __hip_atomic_load(&spro_sum[tid],
                                        __ATOMIC_RELAXED, __HIP_MEMORY_SCOPE_AGENT);
    if (tid == 0)
        u.t.nd = __hip_atomic_load(n_def, __ATOMIC_RELAXED,
                                   __HIP_MEMORY_SCOPE_AGENT);
    __syncthreads();

    if (tid < T_N) {
        // fp[t] = #bg with bucket > t = suffix sum bgh[t+1..T]
        int fp_i = 0;
        for (int k = tid + 1; k < TB; ++k) fp_i += u.t.bgh[k];
        int tot = fp_i;
        for (int k = 0; k <= tid; ++k) tot += u.t.bgh[k];
        float bgt = (float)tot;
        u.t.fpr[tid] = (bgt > 0.0f) ? (float)fp_i / fmaxf(bgt, 1.0f) : 0.0f;
        u.t.ms[tid]  = u.t.ms[tid] / fmaxf((float)u.t.nd, 1.0f);
    }
    __syncthreads();

    if (tid < T_N) {
        // stable ascending argsort via exact rank (ties are bitwise-equal floats)
        float v = u.t.fpr[tid];
        int r = 0;
        for (int j = 0; j < T_N; ++j) {
            float w = u.t.fpr[j];
            r += (w < v) | ((w == v) & (j < tid));
        }
        u.t.order[r] = tid;
    }
    __syncthreads();

    if (tid < T_N - 1) {
        int o0 = u.t.order[tid], o1 = u.t.order[tid + 1];
        double x0 = u.t.fpr[o0], x1 = u.t.fpr[o1];
        double y0 = u.t.ms[o0],  y1 = u.t.ms[o1];
        u.t.contrib[tid] = (x1 - x0) * (y0 + y1) * 0.5;
    } else if (tid < T_N) {
        u.t.contrib[tid] = 0.0;
    }
    __syncthreads();

    if (tid == 0) {
        double ssum = 0.0;
        for (int i = 0; i < T_N - 1; ++i) ssum += u.t.contrib[i];
        out[0] = (float)ssum;
    }
}

extern "C" void kernel_launch(void* const* d_in, const int* in_sizes, int n_in,
                              void* d_out, int out_size, void* d_ws, size_t ws_size,
                              hipStream_t stream) {
    const float* preds  = (const float*)d_in[0];
    const float* thr    = (const float*)d_in[1];
    const int*   labels = (const int*)d_in[2];
    float* out = (float*)d_out;

    int*   region_hist = (int*)d_ws;                        // B*R*TB ints
    int*   bg_hist     = region_hist + B_N * R_N * TB;      // B*TB ints
    float* spro_sum    = (float*)(bg_hist + B_N * TB);      // T floats
    int*   n_def       = (int*)(spro_sum + T_N);            // 1 int
    int*   img_ctr     = n_def + 1;                         // B ints
    int*   done_ctr    = img_ctr + B_N;                     // 1 int

    size_t zbytes = sizeof(int) *
        (size_t)(B_N * R_N * TB + B_N * TB + T_N + 1 + B_N + 1);
    hipMemsetAsync(d_ws, 0, zbytes, stream);

    fused_kernel<<<B_N * CHUNKS, 256, 0, stream>>>(
        preds, labels, thr, region_hist, bg_hist,
        spro_sum, n_def, img_ctr, done_ctr, out);
}

// Round 3
// 215.664 us; speedup vs baseline: 2.5172x; 2.5172x over previous
//
#include <hip/hip_runtime.h>

// Problem constants (match reference setup_inputs)
#define B_N 64
#define H_N 512
#define W_N 512
#define T_N 100
#define TB  101        // T+1 buckets (bucket in [0,100])
#define R_N 8
#define NLAB 9         // labels 0..8 (0 = background)
#define CHUNKS 32      // chunks per image -> grid 2048 = 8 blocks/CU
#define PIX_PER_IMG (H_N * W_N)
#define CPIX (PIX_PER_IMG / CHUNKS)    // 8192 pixels per block
#define NCELL 256      // LUT cells; cell width 1/256 < min threshold spacing

// LUT entry: for cell c (s in ~[c/256,(c+1)/256)):
//   klo = #{thr <= c/256}; at most one threshold per cell, so
//   bucket(s) = klo + (s >= thrb), verified branchlessly against stored
//   neighbors (exact for ANY sorted thresholds via rare fallback).
struct LutE { float tlo, thrb, thi; int klo; };

// ---------------- K1: per-pixel bucket + segmented histogram ----------------
// Latency fix vs R1: double-buffered load batches in NAMED registers with a
// sched_barrier pinning issue order (compiler had collapsed batches: VGPR=24,
// fully serial loads -> VALUBusy 23%). 8 loads in flight per wave.
__global__ __launch_bounds__(256, 8) void hist_kernel(
    const float* __restrict__ preds, const int* __restrict__ labels,
    const float* __restrict__ thr,
    int* __restrict__ region_hist,   // (B, R, TB)
    int* __restrict__ bg_hist)       // (B, TB)
{
    __shared__ float s_thr[T_N];
    __shared__ __align__(16) LutE lut[NCELL];
    __shared__ int whist[4][NLAB * TB];   // per-wave privatized, 14.5 KB

    const int tid  = threadIdx.x;
    const int wave = tid >> 6;

    if (tid < T_N) s_thr[tid] = thr[tid];
    for (int i = tid; i < 4 * NLAB * TB; i += 256) ((int*)whist)[i] = 0;
    __syncthreads();

    if (tid < NCELL) {   // build LUT: binary search per cell
        float lo = (float)tid * (1.0f / (float)NCELL);
        int a = 0, b = T_N;
        while (a < b) { int m = (a + b) >> 1; if (s_thr[m] <= lo) a = m + 1; else b = m; }
        LutE e;
        e.tlo  = (a > 0)       ? s_thr[a - 1] : -2.0f;  // sentinel: always <= s
        e.thrb = (a < T_N)     ? s_thr[a]     :  2.0f;  // sentinel: always  > s
        e.thi  = (a + 1 < T_N) ? s_thr[a + 1] :  2.0f;
        e.klo  = a;
        lut[tid] = e;
    }
    __syncthreads();

    const int img   = blockIdx.x >> 5;          // / CHUNKS
    const int chunk = blockIdx.x & (CHUNKS - 1);
    const long base = (long)img * PIX_PER_IMG + (long)chunk * CPIX;
    const float4* p4 = (const float4*)(preds + base);
    const int4*   l4 = (const int4*)(labels + base);
    int* __restrict__ myh = whist[wave];

    auto PROC = [&](float4 pv, int4 lv) {
        float ps[4] = {pv.x, pv.y, pv.z, pv.w};
        int   ls[4] = {lv.x, lv.y, lv.z, lv.w};
#pragma unroll
        for (int j = 0; j < 4; ++j) {
            float s = ps[j];
            int c = (int)(s * (float)NCELL);
            c = max(0, min(NCELL - 1, c));
            LutE e = lut[c];                     // one ds_read_b128
            bool ge = (s >= e.thrb);
            int k = e.klo + (ge ? 1 : 0);
            float lowv  = ge ? e.thrb : e.tlo;   // = thr[k-1] (or sentinel)
            float highv = ge ? e.thi  : e.thrb;  // = thr[k]   (or sentinel)
            if (__builtin_expect(!(lowv <= s && s < highv), 0)) {
                // exact fixup — never taken for well-formed LUT cells
                k = max(0, min(T_N, k));
                while (k < T_N && s_thr[k] <= s) ++k;
                while (k > 0 && s_thr[k - 1] > s) --k;
            }
            atomicAdd(&myh[ls[j] * TB + k], 1);
        }
    };

    // 32 px/thread = 8 float4 + 8 int4; 4 batches of (2f4+2i4), double-buffered
    float4 pA0 = p4[0 * 256 + tid], pA1 = p4[1 * 256 + tid];
    int4   lA0 = l4[0 * 256 + tid], lA1 = l4[1 * 256 + tid];
#pragma unroll
    for (int g = 0; g < 4; ++g) {
        float4 pB0, pB1; int4 lB0, lB1;
        if (g < 3) {
            const int i0 = (g + 1) * 2;
            pB0 = p4[(i0    ) * 256 + tid]; pB1 = p4[(i0 + 1) * 256 + tid];
            lB0 = l4[(i0    ) * 256 + tid]; lB1 = l4[(i0 + 1) * 256 + tid];
        }
        __builtin_amdgcn_sched_barrier(0);   // loads of batch g+1 issue BEFORE PROC(g)
        PROC(pA0, lA0); PROC(pA1, lA1);
        pA0 = pB0; pA1 = pB1; lA0 = lB0; lA1 = lB1;
    }
    __syncthreads();

    // merge wave copies, flush to global (device-scope atomics, no fences)
    for (int i = tid; i < NLAB * TB; i += 256) {
        int v = whist[0][i] + whist[1][i] + whist[2][i] + whist[3][i];
        if (v) {
            int lab = i / TB;
            int t   = i - lab * TB;
            if (lab == 0)
                atomicAdd(&bg_hist[img * TB + t], v);
            else
                atomicAdd(&region_hist[(img * R_N + (lab - 1)) * TB + t], v);
        }
    }
}

// ---------------- K2: single-block tail (region sPRO + bg fold + AUC) ------
// ONE block, 256 threads, 512 regions = 2/thread. No inter-block sync, no
// device fences (R2 showed __threadfence ~0.22us each on gfx950: L2 writeback).
// Kernel boundary provides hist->tail coherence. All sPRO terms are dyadic
// (tp/2^14) so shuffle-tree accumulation is bit-exact and order-free.
__global__ __launch_bounds__(256) void tail_kernel(
    const int* __restrict__ region_hist,   // (B, R, TB)
    const int* __restrict__ bg_hist,       // (B, TB)
    float* __restrict__ out)
{
    __shared__ float  spro_acc[T_N];
    __shared__ int    nd_acc;
    __shared__ int    bgh[TB];
    __shared__ float  fpr_sh[T_N];
    __shared__ float  ms_sh[T_N];
    __shared__ int    order[T_N];
    __shared__ double contrib[T_N];

    const int tid  = threadIdx.x;
    const int lane = tid & 63;

    if (tid < T_N) spro_acc[tid] = 0.0f;
    if (tid == 0) nd_acc = 0;
    __syncthreads();

    // --- per-region areas (2 regions per thread) ---
    const int* h0 = region_hist + tid * TB;
    const int* h1 = region_hist + (tid + 256) * TB;
    int area0 = 0, area1 = 0;
#pragma unroll 4
    for (int t = 0; t < TB; ++t) { area0 += h0[t]; area1 += h1[t]; }
    const float sat0 = fmaxf((float)area0, 1.0f);
    const float sat1 = fmaxf((float)area1, 1.0f);
    const float val0 = (area0 > 0) ? 1.0f : 0.0f;
    const float val1 = (area1 > 0) ? 1.0f : 0.0f;
    atomicAdd(&nd_acc, (area0 > 0 ? 1 : 0) + (area1 > 0 ? 1 : 0));

    // --- lockstep cumsum over t; wave-reduce contributions; 4-way LDS merge ---
    int cs0 = 0, cs1 = 0;
#pragma unroll 4
    for (int t = 0; t < T_N; ++t) {
        cs0 += h0[t]; cs1 += h1[t];
        float c = fminf((float)(area0 - cs0) / sat0, 1.0f) * val0
                + fminf((float)(area1 - cs1) / sat1, 1.0f) * val1;
#pragma unroll
        for (int off = 32; off; off >>= 1) c += __shfl_down(c, off, 64);
        if (lane == 0) atomicAdd(&spro_acc[t], c);
    }

    // --- fold bg histograms across images ---
    if (tid < TB) {
        int s = 0;
#pragma unroll 4
        for (int b = 0; b < B_N; ++b) s += bg_hist[b * TB + tid];
        bgh[tid] = s;
    }
    __syncthreads();

    if (tid < T_N) {
        // fp[t] = #bg with bucket > t = suffix sum bgh[t+1..T]
        int fp_i = 0;
        for (int k = tid + 1; k < TB; ++k) fp_i += bgh[k];
        int tot = fp_i;
        for (int k = 0; k <= tid; ++k) tot += bgh[k];
        float bgt = (float)tot;
        fpr_sh[tid] = (bgt > 0.0f) ? (float)fp_i / fmaxf(bgt, 1.0f) : 0.0f;
        ms_sh[tid]  = spro_acc[tid] / fmaxf((float)nd_acc, 1.0f);
    }
    __syncthreads();

    if (tid < T_N) {
        // stable ascending argsort via exact rank (ties are bitwise-equal floats)
        float v = fpr_sh[tid];
        int r = 0;
        for (int j = 0; j < T_N; ++j) {
            float w = fpr_sh[j];
            r += (w < v) | ((w == v) & (j < tid));
        }
        order[r] = tid;
    }
    __syncthreads();

    if (tid < T_N - 1) {
        int o0 = order[tid], o1 = order[tid + 1];
        double x0 = fpr_sh[o0], x1 = fpr_sh[o1];
        double y0 = ms_sh[o0],  y1 = ms_sh[o1];
        contrib[tid] = (x1 - x0) * (y0 + y1) * 0.5;
    } else if (tid < T_N) {
        contrib[tid] = 0.0;
    }
    __syncthreads();

    if (tid == 0) {
        double s = 0.0;
        for (int i = 0; i < T_N - 1; ++i) s += contrib[i];
        out[0] = (float)s;
    }
}

extern "C" void kernel_launch(void* const* d_in, const int* in_sizes, int n_in,
                              void* d_out, int out_size, void* d_ws, size_t ws_size,
                              hipStream_t stream) {
    const float* preds  = (const float*)d_in[0];
    const float* thr    = (const float*)d_in[1];
    const int*   labels = (const int*)d_in[2];
    float* out = (float*)d_out;

    int* region_hist = (int*)d_ws;                        // B*R*TB ints
    int* bg_hist     = region_hist + B_N * R_N * TB;      // B*TB ints

    size_t zbytes = sizeof(int) * (size_t)(B_N * R_N * TB + B_N * TB);
    hipMemsetAsync(d_ws, 0, zbytes, stream);

    hist_kernel<<<B_N * CHUNKS, 256, 0, stream>>>(preds, labels, thr,
                                                  region_hist, bg_hist);
    tail_kernel<<<1, 256, 0, stream>>>(region_hist, bg_hist, out);
}

// Round 4
// 205.368 us; speedup vs baseline: 2.6434x; 1.0501x over previous
//
#include <hip/hip_runtime.h>

// Problem constants (match reference setup_inputs)
#define B_N 64
#define H_N 512
#define W_N 512
#define T_N 100
#define TB  101        // T+1 buckets (bucket in [0,100])
#define R_N 8
#define NLAB 9         // labels 0..8 (0 = background)
#define NREG (B_N * R_N)               // 512 regions total
#define CHUNKS 32      // chunks per image -> grid 2048 = 8 blocks/CU
#define PIX_PER_IMG (H_N * W_N)
#define CPIX (PIX_PER_IMG / CHUNKS)    // 8192 pixels per block

// ---------------- K1: per-pixel bucket + segmented histogram ----------------
// Buckets via arithmetic guess k=(int)(s*99)+1 validated against LDS pair
// {thr[k-1], thr[k]} (8B ds_read_b64); binary-search fallback keeps it exact
// for ANY sorted thresholds. 4-deep rotating register pipeline on the global
// loads (statically unrolled -> stays in registers; launch_bounds(256,6)
// gives the VGPR headroom that the VGPR=24 serial versions lacked).
// Flush goes to TRANSPOSED layouts so the tail kernel reads coalesced:
//   rhT[t][img*8 + r]  (TB x 512),  bgT[t][img]  (TB x 64).
__global__ __launch_bounds__(256, 6) void hist_kernel(
    const float* __restrict__ preds, const int* __restrict__ labels,
    const float* __restrict__ thr,
    int* __restrict__ rhT,           // (TB, NREG)
    int* __restrict__ bgT)           // (TB, B_N)
{
    __shared__ float s_thr[T_N];
    __shared__ float2 pairT[TB];          // pairT[k] = {thr[k-1], thr[k]} w/ sentinels
    __shared__ int whist[4][NLAB * TB];   // per-wave privatized, 14.5 KB

    const int tid  = threadIdx.x;
    const int wave = tid >> 6;

    if (tid < T_N) s_thr[tid] = thr[tid];
    for (int i = tid; i < 4 * NLAB * TB; i += 256) ((int*)whist)[i] = 0;
    __syncthreads();

    if (tid < TB) {
        float lo = (tid > 0)   ? s_thr[tid - 1] : -2.0f;  // sentinel: always <= s
        float hi = (tid < T_N) ? s_thr[tid]     :  2.0f;  // sentinel: always  > s
        pairT[tid] = make_float2(lo, hi);
    }
    __syncthreads();

    const int img   = blockIdx.x >> 5;          // / CHUNKS
    const int chunk = blockIdx.x & (CHUNKS - 1);
    const long base = (long)img * PIX_PER_IMG + (long)chunk * CPIX;
    const float4* p4 = (const float4*)(preds + base);
    const int4*   l4 = (const int4*)(labels + base);
    int* __restrict__ myh = whist[wave];

    auto PROC = [&](float4 pv_, int4 lv_) {
        float ps[4] = {pv_.x, pv_.y, pv_.z, pv_.w};
        int   ls[4] = {lv_.x, lv_.y, lv_.z, lv_.w};
#pragma unroll
        for (int j = 0; j < 4; ++j) {
            float s = ps[j];
            int k = (int)(s * (float)(T_N - 1)) + 1;   // guess
            k = max(0, min(T_N, k));
            float2 e = pairT[k];                        // one ds_read_b64
            if (__builtin_expect(!(e.x <= s && s < e.y), 0)) {
                // exact fallback: binary search (authoritative for any thr)
                int a = 0, b = T_N;
                while (a < b) { int m = (a + b) >> 1;
                                if (s_thr[m] <= s) a = m + 1; else b = m; }
                k = a;
            }
            atomicAdd(&myh[ls[j] * TB + k], 1);
        }
    };

    // 32 px/thread = 8 (float4,int4) groups; 4-deep rotating register pipeline.
    float4 pv[4]; int4 lv[4];
#pragma unroll
    for (int q = 0; q < 4; ++q) {
        pv[q] = p4[q * 256 + tid];
        lv[q] = l4[q * 256 + tid];
    }
#pragma unroll
    for (int g = 0; g < 8; ++g) {
        float4 cp = pv[g & 3]; int4 cl = lv[g & 3];
        if (g + 4 < 8) {                      // refill the slot 4 ahead
            pv[g & 3] = p4[(g + 4) * 256 + tid];
            lv[g & 3] = l4[(g + 4) * 256 + tid];
        }
        __builtin_amdgcn_sched_barrier(0);    // pin: refill issues before PROC
        PROC(cp, cl);
    }
    __syncthreads();

    // merge wave copies, flush to global (transposed layouts, device atomics)
    for (int i = tid; i < NLAB * TB; i += 256) {
        int v = whist[0][i] + whist[1][i] + whist[2][i] + whist[3][i];
        if (v) {
            int lab = i / TB;
            int t   = i - lab * TB;
            if (lab == 0)
                atomicAdd(&bgT[t * B_N + img], v);
            else
                atomicAdd(&rhT[t * NREG + img * R_N + (lab - 1)], v);
        }
    }
}

// ---------------- K2: single-block tail, fully coalesced -------------------
// 512 threads, one region per thread. rhT[t*512 + tid] is coalesced for both
// passes (L2-hot, ~206KB). No fences, no cross-block sync (R2: device fences
// cost ~0.22us each on gfx950). All sPRO terms dyadic (tp/2^14) -> shuffle
// tree + LDS atomics are bit-exact and order-free.
__global__ __launch_bounds__(512) void tail_kernel(
    const int* __restrict__ rhT,     // (TB, NREG)
    const int* __restrict__ bgT,     // (TB, B_N)
    float* __restrict__ out)
{
    __shared__ float  spro_acc[T_N];
    __shared__ int    nd_acc;
    __shared__ int    bgh[TB];
    __shared__ float  fpr_sh[T_N];
    __shared__ float  ms_sh[T_N];
    __shared__ int    order[T_N];
    __shared__ double contrib[T_N];

    const int tid  = threadIdx.x;
    const int lane = tid & 63;

    if (tid < T_N) spro_acc[tid] = 0.0f;
    if (tid == 0) nd_acc = 0;
    __syncthreads();

    // --- pass 1: region area (coalesced) ---
    int area = 0;
#pragma unroll 8
    for (int t = 0; t < TB; ++t) area += rhT[t * NREG + tid];

    unsigned long long ball = __ballot(area > 0);
    if (lane == 0) atomicAdd(&nd_acc, __popcll(ball));
    const float sat = fmaxf((float)area, 1.0f);
    const float val = (area > 0) ? 1.0f : 0.0f;

    // --- pass 2: cumsum + sPRO accumulation (coalesced, L2-hot) ---
    int cs = 0;
#pragma unroll 4
    for (int t = 0; t < T_N; ++t) {
        cs += rhT[t * NREG + tid];
        float c = fminf((float)(area - cs) / sat, 1.0f) * val;
#pragma unroll
        for (int off = 32; off; off >>= 1) c += __shfl_down(c, off, 64);
        if (lane == 0) atomicAdd(&spro_acc[t], c);
    }

    // --- fold bg histograms: bgT[t][0..63] is 64 contiguous ints ---
    if (tid < TB) {
        const int4* b4 = (const int4*)&bgT[tid * B_N];
        int s = 0;
#pragma unroll
        for (int q = 0; q < B_N / 4; ++q) {
            int4 v = b4[q];
            s += v.x + v.y + v.z + v.w;
        }
        bgh[tid] = s;
    }
    __syncthreads();

    if (tid < T_N) {
        // fp[t] = #bg with bucket > t = suffix sum bgh[t+1..T]
        int fp_i = 0;
        for (int k = tid + 1; k < TB; ++k) fp_i += bgh[k];
        int tot = fp_i;
        for (int k = 0; k <= tid; ++k) tot += bgh[k];
        float bgt = (float)tot;
        fpr_sh[tid] = (bgt > 0.0f) ? (float)fp_i / fmaxf(bgt, 1.0f) : 0.0f;
        ms_sh[tid]  = spro_acc[tid] / fmaxf((float)nd_acc, 1.0f);
    }
    __syncthreads();

    if (tid < T_N) {
        // stable ascending argsort via exact rank (ties are bitwise-equal floats)
        float v = fpr_sh[tid];
        int r = 0;
        for (int j = 0; j < T_N; ++j) {
            float w = fpr_sh[j];
            r += (w < v) | ((w == v) & (j < tid));
        }
        order[r] = tid;
    }
    __syncthreads();

    if (tid < T_N - 1) {
        int o0 = order[tid], o1 = order[tid + 1];
        double x0 = fpr_sh[o0], x1 = fpr_sh[o1];
        double y0 = ms_sh[o0],  y1 = ms_sh[o1];
        contrib[tid] = (x1 - x0) * (y0 + y1) * 0.5;
    } else if (tid < T_N) {
        contrib[tid] = 0.0;
    }
    __syncthreads();

    if (tid == 0) {
        double s = 0.0;
        for (int i = 0; i < T_N - 1; ++i) s += contrib[i];
        out[0] = (float)s;
    }
}

extern "C" void kernel_launch(void* const* d_in, const int* in_sizes, int n_in,
                              void* d_out, int out_size, void* d_ws, size_t ws_size,
                              hipStream_t stream) {
    const float* preds  = (const float*)d_in[0];
    const float* thr    = (const float*)d_in[1];
    const int*   labels = (const int*)d_in[2];
    float* out = (float*)d_out;

    int* rhT = (int*)d_ws;               // TB * NREG ints (transposed region hists)
    int* bgT = rhT + TB * NREG;          // TB * B_N ints (transposed bg hists)

    size_t zbytes = sizeof(int) * (size_t)(TB * NREG + TB * B_N);
    hipMemsetAsync(d_ws, 0, zbytes, stream);

    hist_kernel<<<B_N * CHUNKS, 256, 0, stream>>>(preds, labels, thr, rhT, bgT);
    tail_kernel<<<1, 512, 0, stream>>>(rhT, bgT, out);
}